// Round 1
// baseline (91.319 us; speedup 1.0000x reference)
//
#include <hip/hip_runtime.h>
#include <hip/hip_bf16.h>

#define NB 8
#define NN 2048
#define DD 128

typedef __attribute__((ext_vector_type(4))) float f32x4;
typedef __attribute__((ext_vector_type(8))) short short8;
typedef __attribute__((ext_vector_type(4))) unsigned int u32x4;

__device__ __forceinline__ unsigned short f2bf_bits(float f) {
  union { __hip_bfloat16 h; unsigned short s; } u;
  u.h = __float2bfloat16(f);
  return u.s;
}

__device__ __forceinline__ short8 cvt8(f32x4 a, f32x4 b) {
  short8 r;
  r[0] = (short)f2bf_bits(a[0]); r[1] = (short)f2bf_bits(a[1]);
  r[2] = (short)f2bf_bits(a[2]); r[3] = (short)f2bf_bits(a[3]);
  r[4] = (short)f2bf_bits(b[0]); r[5] = (short)f2bf_bits(b[1]);
  r[6] = (short)f2bf_bits(b[2]); r[7] = (short)f2bf_bits(b[3]);
  return r;
}

__device__ __forceinline__ void gld16(const void* src, void* lds) {
  __builtin_amdgcn_global_load_lds(
      (const __attribute__((address_space(1))) void*)src,
      (__attribute__((address_space(3))) void*)lds, 16, 0, 0);
}

// ---------- Kernel C: WT[o][d] = bf16(W[d][o]) ----------
__global__ void k_wt(const float* __restrict__ W, short* __restrict__ WT) {
  __shared__ short wl[128 * 132];
  const int t = threadIdx.x;
  const f32x4* ws4 = (const f32x4*)W;  // 4096 float4
#pragma unroll
  for (int i = 0; i < 16; ++i) {
    int e4 = i * 256 + t;
    int dd = e4 >> 5;           // row d (32 float4 per row)
    int oo = (e4 & 31) << 2;    // col o
    f32x4 v = ws4[e4];
    wl[dd * 132 + oo + 0] = (short)f2bf_bits(v[0]);
    wl[dd * 132 + oo + 1] = (short)f2bf_bits(v[1]);
    wl[dd * 132 + oo + 2] = (short)f2bf_bits(v[2]);
    wl[dd * 132 + oo + 3] = (short)f2bf_bits(v[3]);
  }
  __syncthreads();
  const int o = t >> 1, part = t & 1;
  short* dst = WT + (o << 7) + (part << 6);
#pragma unroll
  for (int q = 0; q < 8; ++q) {
    u32x4 u;
#pragma unroll
    for (int p = 0; p < 4; ++p) {
      int d0 = (part << 6) + (q << 3) + (p << 1);
      unsigned lo = (unsigned short)wl[d0 * 132 + o];
      unsigned hi = (unsigned short)wl[(d0 + 1) * 132 + o];
      u[p] = lo | (hi << 16);
    }
    *(u32x4*)(dst + (q << 3)) = u;
  }
}

// ---------- Kernel A1: dnorm[b*N+n] = rsqrt(rowsum(adj)+1e-8) ----------
__global__ void k_degree(const float* __restrict__ adj, float* __restrict__ dnorm) {
  const int wv = threadIdx.x >> 6;
  const int ln = threadIdx.x & 63;
  const int row = blockIdx.x * 4 + wv;  // 0..16383
  const f32x4* rowp = (const f32x4*)(adj + (size_t)row * NN);
  float s = 0.0f;
#pragma unroll
  for (int i = 0; i < 8; ++i) {
    f32x4 v = rowp[i * 64 + ln];
    s += v[0] + v[1] + v[2] + v[3];
  }
#pragma unroll
  for (int off = 32; off >= 1; off >>= 1) s += __shfl_xor(s, off);
  if (ln == 0) dnorm[row] = rsqrtf(s + 1e-8f);
}

// ---------- Kernel A2: yT[b][d][n] = bf16(dnorm[b][n] * x[b][n][d]) ----------
__global__ void k_yt(const float* __restrict__ x, const float* __restrict__ dnorm,
                     short* __restrict__ yT) {
  __shared__ float xl[64 * 129];
  __shared__ float dnl[64];
  const int t = threadIdx.x;
  const int bb = blockIdx.x >> 5;
  const int n0 = (blockIdx.x & 31) << 6;
  if (t < 64) dnl[t] = dnorm[(bb << 11) + n0 + t];
  const f32x4* xs = (const f32x4*)(x + ((size_t)(bb << 11) + n0) * DD);  // 2048 float4
#pragma unroll
  for (int i = 0; i < 8; ++i) {
    int e4 = i * 256 + t;
    int n = e4 >> 5;
    int d = (e4 & 31) << 2;
    f32x4 v = xs[e4];
    xl[n * 129 + d + 0] = v[0];
    xl[n * 129 + d + 1] = v[1];
    xl[n * 129 + d + 2] = v[2];
    xl[n * 129 + d + 3] = v[3];
  }
  __syncthreads();
  const int d = t & 127, half = t >> 7;
  short* dst = yT + (((size_t)(bb << 7) + d) << 11) + n0 + (half << 5);
#pragma unroll
  for (int q = 0; q < 4; ++q) {
    u32x4 u;
#pragma unroll
    for (int p = 0; p < 4; ++p) {
      int n = (half << 5) + (q << 3) + (p << 1);
      float v0 = xl[n * 129 + d] * dnl[n];
      float v1 = xl[(n + 1) * 129 + d] * dnl[n + 1];
      u[p] = (unsigned)f2bf_bits(v0) | ((unsigned)f2bf_bits(v1) << 16);
    }
    *(u32x4*)(dst + (q << 3)) = u;
  }
}

// ---------- Kernel B: fused  out = dnorm_row * (adj @ yT^T) @ W + b ----------
__launch_bounds__(512, 1)
__global__ void k_gemm(const float* __restrict__ adj, const short* __restrict__ yT,
                       const float* __restrict__ dnorm, const short* __restrict__ WT,
                       const float* __restrict__ bias, float* __restrict__ out) {
  __shared__ float adjA[2][4096];   // 2 x [64 rows][64 k] f32, 256B rows, 16 KB each
  __shared__ short yB[2][8192];     // 2 x [128 d][64 k] bf16, 128B rows, 16 KB each

  const int t = threadIdx.x;
  const int ln = t & 63;
  const int wv = t >> 6;              // 0..7
  const int bb = blockIdx.x >> 5;
  const int m0 = (blockIdx.x & 31) << 6;

  const char* adj_blk = (const char*)(adj + (size_t)((bb << 11) + m0) * NN);
  const char* yT_blk = (const char*)(yT + ((size_t)bb * DD) * NN);

  const int oc = (wv << 4) + (ln & 15);   // this wave's output/d column
  const int kgrp = (ln >> 4) << 3;        // k-offset of this lane group
  const unsigned rbase = (unsigned)((ln >> 4) << 2);

  // Preload W fragments (B-operand of epilogue GEMM) and bias
  short8 wf[4];
#pragma unroll
  for (int ks = 0; ks < 4; ++ks)
    wf[ks] = *(const short8*)(WT + oc * DD + ks * 32 + kgrp);
  const float bv = bias[oc];

  f32x4 acc[4];
#pragma unroll
  for (int m = 0; m < 4; ++m) acc[m] = (f32x4)0.0f;

  // stage: global -> LDS, width 16, source pre-swizzled so swizzled ds_reads see
  // linear data (rule #21: gld_lds dest must stay linear)
  auto stage = [&](int c, int tt) {
#pragma unroll
    for (int j = 0; j < 2; ++j) {
      unsigned L = ((unsigned)(wv * 2 + j) << 10) + ((unsigned)ln << 4);
      unsigned row = L >> 8;
      unsigned off = L & 255u;
      unsigned soff = off ^ ((row & 7u) << 4);
      const char* src = adj_blk + (size_t)row * (NN * 4) + (size_t)tt * 256 + soff;
      gld16(src, (char*)&adjA[c][0] + ((unsigned)(wv * 2 + j) << 10));
    }
#pragma unroll
    for (int j = 0; j < 2; ++j) {
      unsigned L = ((unsigned)(wv * 2 + j) << 10) + ((unsigned)ln << 4);
      unsigned d = L >> 7;
      unsigned off = L & 127u;
      unsigned soff = off ^ ((d & 7u) << 4);
      const char* src = yT_blk + (size_t)d * (NN * 2) + (size_t)tt * 128 + soff;
      gld16(src, (char*)&yB[c][0] + ((unsigned)(wv * 2 + j) << 10));
    }
  };

  stage(0, 0);
  __syncthreads();

  for (int tt = 0; tt < 32; ++tt) {
    const int c = tt & 1;
    if (tt < 31) stage(c ^ 1, tt + 1);
#pragma unroll
    for (int ks = 0; ks < 2; ++ks) {
      unsigned dcol = (unsigned)oc;
      unsigned baddr = (dcol << 7) + (unsigned)(ks * 32 + kgrp) * 2;
      baddr ^= (dcol & 7u) << 4;
      short8 bf = *(const short8*)((const char*)&yB[c][0] + baddr);
#pragma unroll
      for (int m = 0; m < 4; ++m) {
        unsigned row = (unsigned)(m * 16 + (ln & 15));
        unsigned a0 = (row << 8) + (unsigned)(ks * 32 + kgrp) * 4;
        unsigned sw = (row & 7u) << 4;
        f32x4 f0 = *(const f32x4*)((const char*)&adjA[c][0] + (a0 ^ sw));
        f32x4 f1 = *(const f32x4*)((const char*)&adjA[c][0] + ((a0 + 16) ^ sw));
        acc[m] = __builtin_amdgcn_mfma_f32_16x16x32_bf16(cvt8(f0, f1), bf, acc[m], 0, 0, 0);
      }
    }
    __syncthreads();
  }

  // Epilogue: row-scale by dnorm, write bf16 support tile to LDS (swizzled)
  short* sup = (short*)&adjA[0][0];  // [64 rows][128 d] bf16, 256B rows
  {
    const unsigned colb = (unsigned)oc * 2;
#pragma unroll
    for (int m = 0; m < 4; ++m) {
      f32x4 dn = *(const f32x4*)(dnorm + (size_t)(bb << 11) + m0 + m * 16 + rbase);
#pragma unroll
      for (int r = 0; r < 4; ++r) {
        unsigned row = (unsigned)(m * 16) + rbase + r;
        unsigned addr = (row << 8) + colb;
        addr ^= (row & 7u) << 4;
        *(short*)((char*)sup + addr) = (short)f2bf_bits(acc[m][r] * dn[r]);
      }
    }
  }
  __syncthreads();

  // Second GEMM: out_tile = support @ W  (K = 128), + bias
  f32x4 acc2[4];
#pragma unroll
  for (int m = 0; m < 4; ++m) acc2[m] = (f32x4)0.0f;
#pragma unroll
  for (int ks = 0; ks < 4; ++ks) {
#pragma unroll
    for (int m = 0; m < 4; ++m) {
      unsigned row = (unsigned)(m * 16 + (ln & 15));
      unsigned addr = (row << 8) + (unsigned)(ks * 32 + kgrp) * 2;
      addr ^= (row & 7u) << 4;
      short8 af = *(const short8*)((const char*)sup + addr);
      acc2[m] = __builtin_amdgcn_mfma_f32_16x16x32_bf16(af, wf[ks], acc2[m], 0, 0, 0);
    }
  }
#pragma unroll
  for (int m = 0; m < 4; ++m) {
#pragma unroll
    for (int r = 0; r < 4; ++r) {
      unsigned row = (unsigned)(m * 16) + rbase + r;
      out[(size_t)((bb << 11) + m0 + row) * DD + oc] = acc2[m][r] + bv;
    }
  }
}

extern "C" void kernel_launch(void* const* d_in, const int* in_sizes, int n_in,
                              void* d_out, int out_size, void* d_ws, size_t ws_size,
                              hipStream_t stream) {
  (void)in_sizes; (void)n_in; (void)out_size; (void)ws_size;
  const float* x = (const float*)d_in[0];
  const float* adj = (const float*)d_in[1];
  const float* W = (const float*)d_in[2];
  const float* bias = (const float*)d_in[3];
  float* out = (float*)d_out;

  char* ws = (char*)d_ws;
  float* dnorm = (float*)ws;                       // 16384 f32 = 64 KB
  short* WT = (short*)(ws + 65536);                // 128x128 bf16 = 32 KB
  short* yT = (short*)(ws + 65536 + 32768);        // 8x128x2048 bf16 = 4 MB

  k_wt<<<1, 256, 0, stream>>>(W, WT);
  k_degree<<<4096, 256, 0, stream>>>(adj, dnorm);
  k_yt<<<256, 256, 0, stream>>>(x, dnorm, yT);
  k_gemm<<<256, 512, 0, stream>>>(adj, yT, dnorm, WT, bias, out);
}

// Round 2
// 71.907 us; speedup vs baseline: 1.2700x; 1.2700x over previous
//
#include <hip/hip_runtime.h>
#include <hip/hip_bf16.h>

#define NN 2048
#define DD 128

typedef __attribute__((ext_vector_type(4))) float f32x4;
typedef __attribute__((ext_vector_type(8))) short short8;
typedef __attribute__((ext_vector_type(2))) unsigned int u32x2;

__device__ __forceinline__ unsigned short f2bf_bits(float f) {
  union { __hip_bfloat16 h; unsigned short s; } u;
  u.h = __float2bfloat16(f);
  return u.s;
}

__device__ __forceinline__ short8 cvt8(f32x4 a, f32x4 b) {
  short8 r;
  r[0] = (short)f2bf_bits(a[0]); r[1] = (short)f2bf_bits(a[1]);
  r[2] = (short)f2bf_bits(a[2]); r[3] = (short)f2bf_bits(a[3]);
  r[4] = (short)f2bf_bits(b[0]); r[5] = (short)f2bf_bits(b[1]);
  r[6] = (short)f2bf_bits(b[2]); r[7] = (short)f2bf_bits(b[3]);
  return r;
}

__device__ __forceinline__ void gld16(const void* src, void* lds) {
  __builtin_amdgcn_global_load_lds(
      (const __attribute__((address_space(1))) void*)src,
      (__attribute__((address_space(3))) void*)lds, 16, 0, 0);
}

// ---------- K1: degree + dnorm + adjS = bf16(dnorm_row * adj) ----------
// one wave per row; row held in 32 VGPR/lane: single read, single write
__global__ void k_degcvt(const float* __restrict__ adj, float* __restrict__ dnorm,
                         short* __restrict__ adjS) {
  const int wv = threadIdx.x >> 6;
  const int ln = threadIdx.x & 63;
  const int row = blockIdx.x * 4 + wv;  // 0..16383
  const f32x4* rowp = (const f32x4*)(adj + (size_t)row * NN);
  f32x4 v[8];
  float s = 0.0f;
#pragma unroll
  for (int i = 0; i < 8; ++i) {
    v[i] = rowp[i * 64 + ln];
    s += v[i][0] + v[i][1] + v[i][2] + v[i][3];
  }
#pragma unroll
  for (int off = 32; off >= 1; off >>= 1) s += __shfl_xor(s, off);
  const float dn = rsqrtf(s + 1e-8f);
  if (ln == 0) dnorm[row] = dn;
  u32x2* orow = (u32x2*)(adjS + (size_t)row * NN);
#pragma unroll
  for (int i = 0; i < 8; ++i) {
    u32x2 u;
    u[0] = (unsigned)f2bf_bits(v[i][0] * dn) | ((unsigned)f2bf_bits(v[i][1] * dn) << 16);
    u[1] = (unsigned)f2bf_bits(v[i][2] * dn) | ((unsigned)f2bf_bits(v[i][3] * dn) << 16);
    orow[i * 64 + ln] = u;
  }
}

// ---------- K2: yT[b][d][n] = bf16(dnorm[n] * (x@W)[n][d]) ----------
// A = W^T (row=dout, k=din) loaded straight from W; B = x rows * dnorm.
// No LDS, no barriers. Output written transposed so K3's B-frags are contiguous.
__global__ void k_y(const float* __restrict__ x, const float* __restrict__ W,
                    const float* __restrict__ dnorm, short* __restrict__ yT) {
  const int ln = threadIdx.x & 63;
  const int wv = threadIdx.x >> 6;          // 4 waves: d rows [wv*32, wv*32+32)
  const int bb = blockIdx.x >> 5;
  const int n0 = (blockIdx.x & 31) << 6;    // 64 n per block
  const int l15 = ln & 15, l4 = ln >> 4;
  const int dbase = wv * 32;

  short8 af[2][4];
#pragma unroll
  for (int dt = 0; dt < 2; ++dt)
#pragma unroll
    for (int ks = 0; ks < 4; ++ks) {
      short8 a;
#pragma unroll
      for (int j = 0; j < 8; ++j)
        a[j] = (short)f2bf_bits(W[(size_t)(ks * 32 + l4 * 8 + j) * DD + dbase + dt * 16 + l15]);
      af[dt][ks] = a;
    }

  f32x4 acc[2][4];
#pragma unroll
  for (int dt = 0; dt < 2; ++dt)
#pragma unroll
    for (int nt = 0; nt < 4; ++nt) acc[dt][nt] = (f32x4)0.0f;

  const float* xb = x + (size_t)bb * NN * DD;
  const float* dnb = dnorm + (size_t)bb * NN;
#pragma unroll
  for (int nt = 0; nt < 4; ++nt) {
    const int n = n0 + nt * 16 + l15;
    const float dn = dnb[n];
#pragma unroll
    for (int ks = 0; ks < 4; ++ks) {
      f32x4 p = *(const f32x4*)(xb + (size_t)n * DD + ks * 32 + l4 * 8);
      f32x4 q = *(const f32x4*)(xb + (size_t)n * DD + ks * 32 + l4 * 8 + 4);
      short8 bf = cvt8(p * dn, q * dn);
#pragma unroll
      for (int dt = 0; dt < 2; ++dt)
        acc[dt][nt] = __builtin_amdgcn_mfma_f32_16x16x32_bf16(af[dt][ks], bf, acc[dt][nt], 0, 0, 0);
    }
  }

  short* yb = yT + (size_t)bb * DD * NN;
#pragma unroll
  for (int dt = 0; dt < 2; ++dt)
#pragma unroll
    for (int nt = 0; nt < 4; ++nt)
#pragma unroll
      for (int r = 0; r < 4; ++r) {
        int d = dbase + dt * 16 + l4 * 4 + r;
        yb[(size_t)d * NN + n0 + nt * 16 + l15] = (short)f2bf_bits(acc[dt][nt][r]);
      }
}

// ---------- K3: out = adjS @ y + b ----------
// BM=64, BK=64, 8 waves (d-split: wave owns 16 output cols). A staged 5 tiles
// ahead (6 LDS bufs, gld_lds 16B, pre-swizzled src + XOR-swizzled reads).
// B from global (L2) 2 tiles ahead into regs. Counted vmcnt, raw barriers.
__launch_bounds__(512, 1)
__global__ void k_gemm(const short* __restrict__ adjS, const short* __restrict__ yT,
                       const float* __restrict__ bias, float* __restrict__ out) {
  __shared__ short As[6][4096];  // 6 x 8 KB: [64 rows][64 k] bf16, 128 B rows

  const int t = threadIdx.x;
  const int ln = t & 63;
  const int wv = t >> 6;
  // XCD-bijective swizzle: grid 256, 8 XCDs -> XCD x owns batch x (yT fits its L2)
  const int orig = ((blockIdx.x & 7) << 5) | (blockIdx.x >> 3);
  const int bb = orig >> 5;
  const int m0 = (orig & 31) << 6;

  const char* ablk = (const char*)(adjS + ((size_t)bb * NN + m0) * NN);
  const int oc = (wv << 4) + (ln & 15);
  const int kg8 = (ln >> 4) << 3;
  const short* ybase = yT + ((size_t)bb * DD + oc) * NN;

  f32x4 acc[4];
#pragma unroll
  for (int m = 0; m < 4; ++m) acc[m] = (f32x4)0.0f;

  auto stage = [&](int tile, int buf) {
    unsigned L = (unsigned)t << 4;             // 0..8176
    unsigned row = L >> 7;
    unsigned off = L & 127u;
    unsigned soff = off ^ ((row & 7u) << 4);
    const char* src = ablk + (size_t)row * (NN * 2) + (size_t)tile * 128 + soff;
    gld16(src, (char*)As + buf * 8192 + L);
  };
  auto loadB = [&](int tile, int ks) {
    return *(const short8*)(ybase + tile * 64 + ks * 32 + kg8);
  };
  auto compute = [&](int buf, short8 bk0, short8 bk1) {
    const char* base = (const char*)As + buf * 8192;
#pragma unroll
    for (int ks = 0; ks < 2; ++ks) {
      short8 bf = ks ? bk1 : bk0;
#pragma unroll
      for (int m = 0; m < 4; ++m) {
        unsigned row = (unsigned)(m * 16 + (ln & 15));
        unsigned c = (unsigned)(ks * 64 + (ln >> 4) * 16);
        short8 a = *(const short8*)(base + (row << 7) + (c ^ ((row & 7u) << 4)));
        acc[m] = __builtin_amdgcn_mfma_f32_16x16x32_bf16(a, bf, acc[m], 0, 0, 0);
      }
    }
  };

  // prologue: tiles 0..4 staged, B(0),B(1) in regs, full drain, barrier
#pragma unroll
  for (int p = 0; p < 5; ++p) stage(p, p);
  short8 b0k0 = loadB(0, 0), b0k1 = loadB(0, 1);
  short8 b1k0 = loadB(1, 0), b1k1 = loadB(1, 1);
  asm volatile("s_waitcnt vmcnt(0)\n\ts_barrier" ::: "memory");

  int cbuf = 0, sbuf = 5;
  for (int tt = 0; tt < 32; tt += 2) {
    // even half-iter: tile tt
    stage((tt + 5) & 31, sbuf);                    // tail wraps: garbage into dead bufs
    short8 n0k0 = loadB((tt + 2) & 31, 0), n0k1 = loadB((tt + 2) & 31, 1);
    compute(cbuf, b0k0, b0k1);
    asm volatile("s_waitcnt vmcnt(12)\n\ts_barrier" ::: "memory");
    cbuf = (cbuf == 5) ? 0 : cbuf + 1;
    sbuf = (sbuf == 5) ? 0 : sbuf + 1;
    // odd half-iter: tile tt+1
    stage((tt + 6) & 31, sbuf);
    short8 n1k0 = loadB((tt + 3) & 31, 0), n1k1 = loadB((tt + 3) & 31, 1);
    compute(cbuf, b1k0, b1k1);
    asm volatile("s_waitcnt vmcnt(12)\n\ts_barrier" ::: "memory");
    cbuf = (cbuf == 5) ? 0 : cbuf + 1;
    sbuf = (sbuf == 5) ? 0 : sbuf + 1;
    b0k0 = n0k0; b0k1 = n0k1; b1k0 = n1k0; b1k1 = n1k1;
  }

  // epilogue: dnorm_row already folded into adjS; just bias + store
  const float bv = bias[oc];
  const int rbase = (ln >> 4) << 2;
#pragma unroll
  for (int m = 0; m < 4; ++m)
#pragma unroll
    for (int r = 0; r < 4; ++r)
      out[(size_t)(bb * NN + m0 + m * 16 + rbase + r) * DD + oc] = acc[m][r] + bv;
}

extern "C" void kernel_launch(void* const* d_in, const int* in_sizes, int n_in,
                              void* d_out, int out_size, void* d_ws, size_t ws_size,
                              hipStream_t stream) {
  (void)in_sizes; (void)n_in; (void)out_size; (void)ws_size;
  const float* x = (const float*)d_in[0];
  const float* adj = (const float*)d_in[1];
  const float* W = (const float*)d_in[2];
  const float* bias = (const float*)d_in[3];
  float* out = (float*)d_out;

  char* ws = (char*)d_ws;
  float* dnorm = (float*)ws;                          // 64 KB
  short* yT = (short*)(ws + (1 << 16));               // 4 MB
  short* adjS = (short*)(ws + (1 << 16) + (4 << 20)); // 67 MB

  k_degcvt<<<4096, 256, 0, stream>>>(adj, dnorm, adjS);
  k_y<<<256, 256, 0, stream>>>(x, W, dnorm, yT);
  k_gemm<<<256, 512, 0, stream>>>(adjS, yT, bias, out);
}

// Round 3
// 69.246 us; speedup vs baseline: 1.3188x; 1.0384x over previous
//
#include <hip/hip_runtime.h>
#include <hip/hip_bf16.h>

#define NN 2048
#define DD 128

typedef __attribute__((ext_vector_type(4))) float f32x4;
typedef __attribute__((ext_vector_type(8))) short short8;
typedef __attribute__((ext_vector_type(2))) unsigned int u32x2;

__device__ __forceinline__ unsigned short f2bf_bits(float f) {
  union { __hip_bfloat16 h; unsigned short s; } u;
  u.h = __float2bfloat16(f);
  return u.s;
}

__device__ __forceinline__ short8 cvt8(f32x4 a, f32x4 b) {
  short8 r;
  r[0] = (short)f2bf_bits(a[0]); r[1] = (short)f2bf_bits(a[1]);
  r[2] = (short)f2bf_bits(a[2]); r[3] = (short)f2bf_bits(a[3]);
  r[4] = (short)f2bf_bits(b[0]); r[5] = (short)f2bf_bits(b[1]);
  r[6] = (short)f2bf_bits(b[2]); r[7] = (short)f2bf_bits(b[3]);
  return r;
}

// ---------- K1: dnorm[b*N+n] = rsqrt(rowsum(adj)+1e-8) ---------- (pure read)
__global__ void k_degree(const float* __restrict__ adj, float* __restrict__ dnorm) {
  const int wv = threadIdx.x >> 6;
  const int ln = threadIdx.x & 63;
  const int row = blockIdx.x * 4 + wv;  // 0..16383
  const f32x4* rowp = (const f32x4*)(adj + (size_t)row * NN);
  float s = 0.0f;
#pragma unroll
  for (int i = 0; i < 8; ++i) {
    f32x4 v = rowp[i * 64 + ln];
    s += v[0] + v[1] + v[2] + v[3];
  }
#pragma unroll
  for (int off = 32; off >= 1; off >>= 1) s += __shfl_xor(s, off);
  if (ln == 0) dnorm[row] = rsqrtf(s + 1e-8f);
}

// ---------- K2: yT[b][d][n] = bf16(dnorm[n] * (x@W)[n][d]) ----------
__global__ void k_y(const float* __restrict__ x, const float* __restrict__ W,
                    const float* __restrict__ dnorm, short* __restrict__ yT) {
  const int ln = threadIdx.x & 63;
  const int wv = threadIdx.x >> 6;          // 4 waves: d rows [wv*32, wv*32+32)
  const int bb = blockIdx.x >> 5;
  const int n0 = (blockIdx.x & 31) << 6;    // 64 n per block
  const int l15 = ln & 15, l4 = ln >> 4;
  const int dbase = wv * 32;

  short8 af[2][4];
#pragma unroll
  for (int dt = 0; dt < 2; ++dt)
#pragma unroll
    for (int ks = 0; ks < 4; ++ks) {
      short8 a;
#pragma unroll
      for (int j = 0; j < 8; ++j)
        a[j] = (short)f2bf_bits(W[(size_t)(ks * 32 + l4 * 8 + j) * DD + dbase + dt * 16 + l15]);
      af[dt][ks] = a;
    }

  f32x4 acc[2][4];
#pragma unroll
  for (int dt = 0; dt < 2; ++dt)
#pragma unroll
    for (int nt = 0; nt < 4; ++nt) acc[dt][nt] = (f32x4)0.0f;

  const float* xb = x + (size_t)bb * NN * DD;
  const float* dnb = dnorm + (size_t)bb * NN;
#pragma unroll
  for (int nt = 0; nt < 4; ++nt) {
    const int n = n0 + nt * 16 + l15;
    const float dn = dnb[n];
#pragma unroll
    for (int ks = 0; ks < 4; ++ks) {
      f32x4 p = *(const f32x4*)(xb + (size_t)n * DD + ks * 32 + l4 * 8);
      f32x4 q = *(const f32x4*)(xb + (size_t)n * DD + ks * 32 + l4 * 8 + 4);
      short8 bf = cvt8(p * dn, q * dn);
#pragma unroll
      for (int dt = 0; dt < 2; ++dt)
        acc[dt][nt] = __builtin_amdgcn_mfma_f32_16x16x32_bf16(af[dt][ks], bf, acc[dt][nt], 0, 0, 0);
    }
  }

  short* yb = yT + (size_t)bb * DD * NN;
#pragma unroll
  for (int dt = 0; dt < 2; ++dt)
#pragma unroll
    for (int nt = 0; nt < 4; ++nt)
#pragma unroll
      for (int r = 0; r < 4; ++r) {
        int d = dbase + dt * 16 + l4 * 4 + r;
        yb[(size_t)d * NN + n0 + nt * 16 + l15] = (short)f2bf_bits(acc[dt][nt][r]);
      }
}

// ---------- K3: out[n][:] = dnorm[n] * (adj[n,:] @ y) + b ----------
// BM=32, BK=64, 512 thr, grid 512 (2 blocks/CU, 4 waves/SIMD).
// adj f32 read from L3 (left resident by K1), reg-staged: global->reg->cvt->
// ds_write bf16 (T14). Depth-4 A regs, depth-2 B regs, NBUF=4 LDS ring,
// raw barriers + lgkmcnt(0) only; compiler emits counted vmcnt at uses.
__launch_bounds__(512, 4)
__global__ void k_gemm(const float* __restrict__ adj, const short* __restrict__ yT,
                       const float* __restrict__ dnorm, const float* __restrict__ bias,
                       float* __restrict__ out) {
  __shared__ short As[4][2048];  // 4 x 4 KB: [32 rows][64 k] bf16, 128 B rows

  const int t = threadIdx.x;
  const int ln = t & 63;
  const int wv = t >> 6;
  // XCD-bijective swizzle: XCD x owns batch x (its 4 MB yT slice stays in L2)
  const int orig = ((blockIdx.x & 7) << 6) | (blockIdx.x >> 3);
  const int bb = orig >> 6;             // batch
  const int m0 = (orig & 63) << 5;      // row block (32 rows)

  const float* ablk = adj + ((size_t)bb * NN + m0) * NN;
  const int oc = (wv << 4) + (ln & 15);       // this wave's output/d column
  const int kg8 = (ln >> 4) << 3;             // k-offset within 32-k MFMA step
  const short* ybase = yT + ((size_t)bb * DD + oc) * NN;

  const unsigned srow = (unsigned)t >> 4;         // staging row 0..31
  const unsigned sc4 = ((unsigned)t & 15u) << 2;  // staging f32 col

  f32x4 acc[2];
  acc[0] = (f32x4)0.0f; acc[1] = (f32x4)0.0f;

  auto loadA = [&](int tile) -> f32x4 {
    return *(const f32x4*)(ablk + (size_t)srow * NN + ((tile & 31) << 6) + sc4);
  };
  auto loadB = [&](int tile, int ks) -> short8 {
    return *(const short8*)(ybase + ((tile & 31) << 6) + ks * 32 + kg8);
  };
  auto writeA = [&](f32x4 v, int buf) {
    unsigned byte = (srow << 7) + (sc4 << 1);
    byte ^= (srow & 7u) << 4;
    u32x2 u;
    u[0] = (unsigned)f2bf_bits(v[0]) | ((unsigned)f2bf_bits(v[1]) << 16);
    u[1] = (unsigned)f2bf_bits(v[2]) | ((unsigned)f2bf_bits(v[3]) << 16);
    *(u32x2*)((char*)As + (buf << 12) + byte) = u;
  };
  auto compute = [&](int buf, short8 b0, short8 b1) {
    const char* base = (const char*)As + (buf << 12);
#pragma unroll
    for (int ks = 0; ks < 2; ++ks) {
      short8 bf = ks ? b1 : b0;
#pragma unroll
      for (int m = 0; m < 2; ++m) {
        unsigned row = (unsigned)(m * 16 + (ln & 15));
        unsigned byte = (row << 7) + (unsigned)((ks * 32 + kg8) << 1);
        byte ^= (row & 7u) << 4;
        short8 a = *(const short8*)(base + byte);
        acc[m] = __builtin_amdgcn_mfma_f32_16x16x32_bf16(a, bf, acc[m], 0, 0, 0);
      }
    }
  };

  // prologue: A(0..3) in regs, B(0),B(1) in regs, tile 0 in LDS
  f32x4 sA0 = loadA(0), sA1 = loadA(1), sA2 = loadA(2), sA3 = loadA(3);
  short8 bE0 = loadB(0, 0), bE1 = loadB(0, 1);
  short8 bO0 = loadB(1, 0), bO1 = loadB(1, 1);
  writeA(sA0, 0);
  asm volatile("s_waitcnt lgkmcnt(0)\n\ts_barrier" ::: "memory");

#define GITER(T, SNEW, SWR, BC0, BC1)                                 \
  {                                                                   \
    SNEW = loadA((T) + 4);                                            \
    short8 nb0 = loadB((T) + 2, 0), nb1 = loadB((T) + 2, 1);          \
    writeA(SWR, ((T) + 1) & 3);                                       \
    asm volatile("s_waitcnt lgkmcnt(0)\n\ts_barrier" ::: "memory");   \
    compute((T) & 3, BC0, BC1);                                       \
    BC0 = nb0; BC1 = nb1;                                             \
  }

#pragma unroll 1
  for (int t4 = 0; t4 < 32; t4 += 4) {
    GITER(t4 + 0, sA0, sA1, bE0, bE1);
    GITER(t4 + 1, sA1, sA2, bO0, bO1);
    GITER(t4 + 2, sA2, sA3, bE0, bE1);
    GITER(t4 + 3, sA3, sA0, bO0, bO1);
  }
#undef GITER

  // epilogue: out = dnorm_row * acc + bias
  const float bv = bias[oc];
  const int rbase = (ln >> 4) << 2;
#pragma unroll
  for (int m = 0; m < 2; ++m) {
    f32x4 dn = *(const f32x4*)(dnorm + (size_t)bb * NN + m0 + m * 16 + rbase);
#pragma unroll
    for (int r = 0; r < 4; ++r)
      out[(size_t)(bb * NN + m0 + m * 16 + rbase + r) * DD + oc] = acc[m][r] * dn[r] + bv;
  }
}

extern "C" void kernel_launch(void* const* d_in, const int* in_sizes, int n_in,
                              void* d_out, int out_size, void* d_ws, size_t ws_size,
                              hipStream_t stream) {
  (void)in_sizes; (void)n_in; (void)out_size; (void)ws_size;
  const float* x = (const float*)d_in[0];
  const float* adj = (const float*)d_in[1];
  const float* W = (const float*)d_in[2];
  const float* bias = (const float*)d_in[3];
  float* out = (float*)d_out;

  char* ws = (char*)d_ws;
  float* dnorm = (float*)ws;                 // 64 KB
  short* yT = (short*)(ws + (1 << 16));      // 4 MB

  k_degree<<<4096, 256, 0, stream>>>(adj, dnorm);
  k_y<<<256, 256, 0, stream>>>(x, W, dnorm, yT);
  k_gemm<<<512, 512, 0, stream>>>(adj, yT, dnorm, bias, out);
}